// Round 3
// baseline (413.658 us; speedup 1.0000x reference)
//
#include <hip/hip_runtime.h>
#include <stdint.h>
#include <math.h>

#define DIMC 2048
#define NHEADS 16
#define HDIM 128
#define TSEQ 2048
#define NTOK 4096   // B*T

using bf16x8 = __attribute__((ext_vector_type(8))) short;
using f32x4  = __attribute__((ext_vector_type(4))) float;

typedef __attribute__((address_space(1))) const void gas_void;
typedef __attribute__((address_space(3))) void las_void;

static __device__ __forceinline__ unsigned short f2b(float f) {
  union { float f; unsigned int u; } a; a.f = f;
  unsigned int u = a.u;
  u = (u + 0x7fffu + ((u >> 16) & 1u)) >> 16;   // RNE
  return (unsigned short)u;
}
static __device__ __forceinline__ float b2f(unsigned short s) {
  union { unsigned int u; float f; } a; a.u = ((unsigned int)s) << 16;
  return a.f;
}

// wave-uniform input dtype detect (bf16 vs fp32) from x's first 128 shorts.
// 256B read is L2-broadcast after the first block; replaces the detect
// kernel + flag round-trip (dispatch-count reduction).
static __device__ __forceinline__ int detect_inline(const void* __restrict__ x)
{
  const int lane = threadIdx.x & 63;
  const unsigned short u = ((const unsigned short*)x)[2 * lane];
  const int e = (u >> 7) & 0xFF;
  const unsigned long long m = __ballot((e >= 112) && (e <= 135));
  return (__popcll(m) >= 32) ? 1 : 0;
}

// ---------------- ternary dequant core (dtype-flag branched) --------------
static __device__ __forceinline__ void dequant_one(
    const void* __restrict__ w, unsigned short* __restrict__ o,
    int grp, int lane, int isbf16)
{
  float a, bq;
  if (isbf16) {
    const unsigned int pk =
        ((const unsigned int*)((const unsigned short*)w + (long)grp * 128))[lane];
    a  = b2f((unsigned short)(pk & 0xffffu));
    bq = b2f((unsigned short)(pk >> 16));
  } else {
    const float2 v = ((const float2*)((const float*)w + (long)grp * 128))[lane];
    a = v.x; bq = v.y;
  }
  double s = fabs((double)a) + fabs((double)bq);
  #pragma unroll
  for (int off = 1; off < 64; off <<= 1) s += __shfl_xor(s, off);
  double scale = s * (1.0 / 128.0);
  if (scale < 1e-8) scale = 1e-8;
  const float fs = (float)scale;
  const double wn0 = (double)a / scale;
  const double wn1 = (double)bq / scale;
  const float q0 = (wn0 > 0.5) ? fs : ((wn0 < -0.5) ? -fs : 0.0f);
  const float q1 = (wn1 > 0.5) ? fs : ((wn1 < -0.5) ? -fs : 0.0f);
  const unsigned int opk = (unsigned int)f2b(q0) | ((unsigned int)f2b(q1) << 16);
  ((unsigned int*)o)[(long)grp * 64 + lane] = opk;
}

// fused prep: y=0 cast x->bf16; y=1..3 dequant wq/wk/wv into row-stacked
// [6144][2048]; y=4 (only when ws has room) dequant wo into its own buffer.
__global__ void __launch_bounds__(256) prep(
    const void* __restrict__ x,
    const void* __restrict__ w0, const void* __restrict__ w1,
    const void* __restrict__ w2, const void* __restrict__ w3,
    unsigned short* __restrict__ xb, unsigned short* __restrict__ wqkv,
    unsigned short* __restrict__ wob)
{
  const int isbf16 = detect_inline(x);
  const int wave = threadIdx.x >> 6, lane = threadIdx.x & 63;
  const int y = blockIdx.y;
  if (y == 0) {
    const int i = (blockIdx.x * 256 + threadIdx.x) * 4;
    if (isbf16) {
      *(ushort4*)(xb + i) = *(const ushort4*)((const unsigned short*)x + i);
    } else {
      const float4 v = *(const float4*)((const float*)x + i);
      ushort4 u;
      u.x = f2b(v.x); u.y = f2b(v.y); u.z = f2b(v.z); u.w = f2b(v.w);
      *(ushort4*)(xb + i) = u;
    }
  } else if (y <= 3) {
    const void* w = (y == 1) ? w0 : (y == 2) ? w1 : w2;
    dequant_one(w, wqkv + (long)(y - 1) * DIMC * DIMC,
                blockIdx.x * 4 + wave, lane, isbf16);
  } else {
    dequant_one(w3, wob, blockIdx.x * 4 + wave, lane, isbf16);
  }
}

// fallback wo-dequant (inline flag) when ws can't host a separate wo buffer
__global__ void __launch_bounds__(256) dequant_auto(
    const void* __restrict__ w, const void* __restrict__ x,
    unsigned short* __restrict__ o)
{
  const int isbf16 = detect_inline(x);
  dequant_one(w, o, blockIdx.x * 4 + (threadIdx.x >> 6), threadIdx.x & 63,
              isbf16);
}

// ---------------- bf16 GEMM, C[m,n] = sum_k A[m,k]*B[n,k] (B^T input) -----
// BK=64 variant of the m97 structure: 128x128 tile. Proven 123-124 us for
// QKV; the 256^2 8-phase port measured SLOWER (129 us: 1.5-round grid
// quantization at 1 block/CU + unhidden stalls at 2 waves/SIMD) — keep
// multi-block TLP latency hiding instead.
__device__ __forceinline__ void storeOne(float* C, long i, float v) { C[i] = v; }
__device__ __forceinline__ void storeOne(unsigned short* C, long i, float v) { C[i] = f2b(v); }

template <typename OUTT>
static __device__ __forceinline__ void gemm_tile(
    const unsigned short* __restrict__ A, const unsigned short* __restrict__ B,
    OUTT* __restrict__ C, int m0, int n0, int Nc, int K,
    unsigned short* As, unsigned short* Bs)   // each 128*64 elems (2 half-panels)
{
  const int tid = threadIdx.x;
  const int wave = tid >> 6;
  const int lane = tid & 63;
  const int wr = (wave >> 1) * 64, wc = (wave & 1) * 64;
  const int c16 = lane & 15, q4 = lane >> 4;

  f32x4 acc[4][4];
  #pragma unroll
  for (int i = 0; i < 4; i++)
    #pragma unroll
    for (int j = 0; j < 4; j++)
      acc[i][j] = (f32x4){0.f, 0.f, 0.f, 0.f};

  const int srow = tid >> 2;            // 0..63
  const int scol = (tid & 3) * 8;       // 16 B chunk within a 32-col half
  const unsigned short* ga = A + (long)(m0 + srow) * K + scol;
  const unsigned short* gb = B + (long)(n0 + srow) * K + scol;

  for (int k0 = 0; k0 < K; k0 += 64) {
    #pragma unroll
    for (int h = 0; h < 2; h++)             // k-half: cols k0+h*32
      #pragma unroll
      for (int i = 0; i < 2; i++) {         // row-half: rows i*64
        __builtin_amdgcn_global_load_lds(
            (gas_void*)(ga + (long)i * 64 * K + k0 + h * 32),
            (las_void*)(As + h * 4096 + i * 2048 + wave * 512), 16, 0, 0);
        __builtin_amdgcn_global_load_lds(
            (gas_void*)(gb + (long)i * 64 * K + k0 + h * 32),
            (las_void*)(Bs + h * 4096 + i * 2048 + wave * 512), 16, 0, 0);
      }
    __syncthreads();
    #pragma unroll
    for (int kc = 0; kc < 2; kc++) {
      bf16x8 af[4], bfr[4];
      #pragma unroll
      for (int t = 0; t < 4; t++) {
        af[t]  = *(const bf16x8*)(As + kc * 4096 + (wr + t * 16 + c16) * 32 + q4 * 8);
        bfr[t] = *(const bf16x8*)(Bs + kc * 4096 + (wc + t * 16 + c16) * 32 + q4 * 8);
      }
      #pragma unroll
      for (int mt = 0; mt < 4; mt++)
        #pragma unroll
        for (int nt = 0; nt < 4; nt++)
          acc[mt][nt] = __builtin_amdgcn_mfma_f32_16x16x32_bf16(af[mt], bfr[nt], acc[mt][nt], 0, 0, 0);
    }
    __syncthreads();
  }

  // C/D layout (m89-verified): n = lane&15, m = (lane>>4)*4 + reg
  #pragma unroll
  for (int mt = 0; mt < 4; mt++) {
    const int m = m0 + wr + mt * 16 + q4 * 4;
    #pragma unroll
    for (int nt = 0; nt < 4; nt++) {
      const int n = wc + nt * 16 + c16;   // caller pre-offsets C to its n0
      #pragma unroll
      for (int r = 0; r < 4; r++)
        storeOne(C, (long)(m + r) * Nc + n, acc[mt][nt][r]);
    }
  }
}

template <typename OUTT>
__global__ void __launch_bounds__(256) gemm_bt(
    const unsigned short* __restrict__ A, const unsigned short* __restrict__ B,
    OUTT* __restrict__ C, int M, int N, int K)
{
  __shared__ unsigned short As[128 * 64];
  __shared__ unsigned short Bs[128 * 64];
  gemm_tile<OUTT>(A, B, C + blockIdx.x * 128, blockIdx.y * 128, blockIdx.x * 128,
                  N, K, As, Bs);
}

// fused QKV: B row-stacked [6144][2048]; 128-col slab routed per buffer
__global__ void __launch_bounds__(256) gemm_qkv(
    const unsigned short* __restrict__ A, const unsigned short* __restrict__ B,
    unsigned short* __restrict__ C0, unsigned short* __restrict__ C1,
    unsigned short* __restrict__ C2, int K)
{
  __shared__ unsigned short As[128 * 64];
  __shared__ unsigned short Bs[128 * 64];
  const int n0 = blockIdx.x * 128;                 // 0..6143
  unsigned short* Cb = (n0 < 2048) ? C0 : (n0 < 4096) ? C1 : C2;
  gemm_tile<unsigned short>(A, B, Cb + (n0 & 2047), blockIdx.y * 128, n0,
                            DIMC, K, As, Bs);
}

// ---------------- RoPE in-place on Q and K (bf16) ----------------
__global__ void __launch_bounds__(256) rope_kernel(
    unsigned short* __restrict__ Q, unsigned short* __restrict__ Kb)
{
  const int idx = blockIdx.x * 256 + threadIdx.x;
  const int d = idx & 63;
  const int h = (idx >> 6) & (NHEADS - 1);
  const int row = idx >> 10;
  const int t = row & (TSEQ - 1);
  const float inv_freq = expf(-9.210340371976184f * (float)d * (1.0f / 64.0f));
  float sn, cs;
  sincosf((float)t * inv_freq, &sn, &cs);
  const long base = (long)row * DIMC + h * HDIM + d;
  float x1 = b2f(Q[base]), x2 = b2f(Q[base + 64]);
  Q[base]      = f2b(x1 * cs - x2 * sn);
  Q[base + 64] = f2b(x1 * sn + x2 * cs);
  x1 = b2f(Kb[base]); x2 = b2f(Kb[base + 64]);
  Kb[base]      = f2b(x1 * cs - x2 * sn);
  Kb[base + 64] = f2b(x1 * sn + x2 * cs);
}

// ---------------- flash attention (causal), bf16 MFMA ----------------
// Round-0 structure (plain __syncthreads, no setprio — the r2 bundle of
// raw-barrier+setprio measured +10us: setprio is m190's lockstep-negative
// regime here). NEW: XOR-swizzled LDS layouts. The old padded strides
// (136/72 shorts) put rows 4 banks apart -> ds_read_b128 lanes landed
// 8-per-bank (8-way conflict, ~2.9x cost) on the K-read, V-read and
// P-read paths — the dominant per-tile cost (~1000 cyc vs 320 cyc MFMA).
// Linear strides (128/64 shorts) + idx ^= (row&7)<<3 (16B granule) put
// every access pattern at <=2 lanes/bank (free). Bit-exact layout change.
static __device__ __forceinline__ int swz(int row, int idx) {
  return idx ^ ((row & 7) << 3);
}
#define FA_M 16.0f
__global__ void __launch_bounds__(256) fattn(
    const unsigned short* __restrict__ Q,
    const unsigned short* __restrict__ K,
    const unsigned short* __restrict__ V,
    unsigned short* __restrict__ Y)
{
  __shared__ unsigned short SU[8192];       // 16 KB union: K[64][128] | P[128][64]
  __shared__ unsigned short VT[8192];       // 16 KB: V^T [128][64]
  __shared__ float red[4][32];

  const int tid = threadIdx.x, wave = tid >> 6, lane = tid & 63;
  const int idx = blockIdx.x;               // 512 blocks
  const int qt = 15 - (idx >> 5);           // heaviest (qt=15) first
  const int bh = idx & 31;
  const int b = bh >> 4, h = bh & 15;
  const int qbase = qt * 128;
  const int qw = wave * 32;
  const int c = lane & 15, g = lane >> 4;
  const long tokbase = (long)b * TSEQ;
  const int col0 = h * HDIM;

  bf16x8 qf[2][4];
  #pragma unroll
  for (int qq = 0; qq < 2; qq++) {
    const unsigned short* qp =
        Q + (tokbase + qbase + qw + qq * 16 + c) * DIMC + col0 + g * 8;
    #pragma unroll
    for (int kc = 0; kc < 4; kc++) qf[qq][kc] = *(const bf16x8*)(qp + kc * 32);
  }

  f32x4 od[8][2];
  #pragma unroll
  for (int dt = 0; dt < 8; dt++)
    #pragma unroll
    for (int qq = 0; qq < 2; qq++)
      od[dt][qq] = (f32x4){0.f, 0.f, 0.f, 0.f};
  float lpart[2][4];
  #pragma unroll
  for (int qq = 0; qq < 2; qq++)
    #pragma unroll
    for (int r = 0; r < 4; r++) lpart[qq][r] = 0.0f;

  const int ksr = tid >> 2, ksc = (tid & 3) * 32;   // K stage: row, short-col
  const int vk0 = (tid & 31) * 2, vd0 = (tid >> 5) * 16;

  const float SC = 0.088388347648318447f;  // 1/sqrt(128)
  const int nkt = 2 * qt + 2;

  // prefetch registers (K row chunk: 4x float4; V: 2 keys x 16 d)
  float4 kr0, kr1, kr2, kr3;
  bf16x8 va0, va1, vb0, vb1;
  {
    const unsigned short* src = K + (tokbase + ksr) * DIMC + col0 + ksc;
    kr0 = ((const float4*)src)[0]; kr1 = ((const float4*)src)[1];
    kr2 = ((const float4*)src)[2]; kr3 = ((const float4*)src)[3];
    const unsigned short* s0 = V + (tokbase + vk0) * DIMC + col0 + vd0;
    const unsigned short* s1 = s0 + DIMC;
    va0 = *(const bf16x8*)(s0); va1 = *(const bf16x8*)(s0 + 8);
    vb0 = *(const bf16x8*)(s1); vb1 = *(const bf16x8*)(s1 + 8);
  }

  for (int kt = 0; kt < nkt; kt++) {
    const int kb = kt * 64;
    __syncthreads();   // A: prev-iter readers done with SU/VT
    {
      unsigned short* krow = &SU[ksr * 128];
      *(float4*)&krow[swz(ksr, ksc + 0)]  = kr0;
      *(float4*)&krow[swz(ksr, ksc + 8)]  = kr1;
      *(float4*)&krow[swz(ksr, ksc + 16)] = kr2;
      *(float4*)&krow[swz(ksr, ksc + 24)] = kr3;
    }
    {
      #pragma unroll
      for (int dd = 0; dd < 8; dd++) {
        const unsigned int p0 =
            (unsigned int)(unsigned short)va0[dd] |
            ((unsigned int)(unsigned short)vb0[dd] << 16);
        *(unsigned int*)&VT[(vd0 + dd) * 64 + swz(vd0 + dd, vk0)] = p0;
      }
      #pragma unroll
      for (int dd = 0; dd < 8; dd++) {
        const unsigned int p1 =
            (unsigned int)(unsigned short)va1[dd] |
            ((unsigned int)(unsigned short)vb1[dd] << 16);
        *(unsigned int*)&VT[(vd0 + 8 + dd) * 64 + swz(vd0 + 8 + dd, vk0)] = p1;
      }
    }
    __syncthreads();   // B: staging visible

    if (kt + 1 < nkt) {   // issue next tile's loads
      const int kb2 = kb + 64;
      const unsigned short* src = K + (tokbase + kb2 + ksr) * DIMC + col0 + ksc;
      kr0 = ((const float4*)src)[0]; kr1 = ((const float4*)src)[1];
      kr2 = ((const float4*)src)[2]; kr3 = ((const float4*)src)[3];
      const unsigned short* s0 = V + (tokbase + kb2 + vk0) * DIMC + col0 + vd0;
      const unsigned short* s1 = s0 + DIMC;
      va0 = *(const bf16x8*)(s0); va1 = *(const bf16x8*)(s0 + 8);
      vb0 = *(const bf16x8*)(s1); vb1 = *(const bf16x8*)(s1 + 8);
    }

    f32x4 sacc[2][4];
    #pragma unroll
    for (int qq = 0; qq < 2; qq++)
      #pragma unroll
      for (int nt = 0; nt < 4; nt++) sacc[qq][nt] = (f32x4){0.f, 0.f, 0.f, 0.f};
    #pragma unroll
    for (int kc = 0; kc < 4; kc++) {
      bf16x8 bk[4];
      #pragma unroll
      for (int nt = 0; nt < 4; nt++) {
        const int kr = nt * 16 + c;
        bk[nt] = *(const bf16x8*)&SU[kr * 128 + swz(kr, kc * 32 + g * 8)];
      }
      #pragma unroll
      for (int qq = 0; qq < 2; qq++)
        #pragma unroll
        for (int nt = 0; nt < 4; nt++)
          sacc[qq][nt] = __builtin_amdgcn_mfma_f32_16x16x32_bf16(
              qf[qq][kc], bk[nt], sacc[qq][nt], 0, 0, 0);
    }
    __syncthreads();   // C: Ks reads done before Ps overwrites SU

    #pragma unroll
    for (int qq = 0; qq < 2; qq++)
      #pragma unroll
      for (int r = 0; r < 4; r++) {
        const int qg = qbase + qw + qq * 16 + g * 4 + r;
        const int prow = qw + qq * 16 + g * 4 + r;
        #pragma unroll
        for (int nt = 0; nt < 4; nt++) {
          const int kg = kb + nt * 16 + c;
          const float sv = sacc[qq][nt][r] * SC - FA_M;
          const float p = (kg > qg) ? 0.0f : __expf(sv);
          lpart[qq][r] += p;
          SU[prow * 64 + swz(prow, nt * 16 + c)] = f2b(p);
        }
      }

    #pragma unroll
    for (int kc = 0; kc < 2; kc++) {
      bf16x8 pb[2];
      #pragma unroll
      for (int qq = 0; qq < 2; qq++) {
        const int prow = qw + qq * 16 + c;
        pb[qq] = *(const bf16x8*)&SU[prow * 64 + swz(prow, kc * 32 + g * 8)];
      }
      #pragma unroll
      for (int dt = 0; dt < 8; dt++) {
        const int vr = dt * 16 + c;
        bf16x8 va = *(const bf16x8*)&VT[vr * 64 + swz(vr, kc * 32 + g * 8)];
        #pragma unroll
        for (int qq = 0; qq < 2; qq++)
          od[dt][qq] = __builtin_amdgcn_mfma_f32_16x16x32_bf16(
              va, pb[qq], od[dt][qq], 0, 0, 0);
      }
    }
  }

  #pragma unroll
  for (int qq = 0; qq < 2; qq++)
    #pragma unroll
    for (int r = 0; r < 4; r++) {
      float l = lpart[qq][r];
      #pragma unroll
      for (int off = 1; off < 16; off <<= 1) l += __shfl_xor(l, off);
      lpart[qq][r] = l;
    }
  __syncthreads();
  if (c == 0) {
    #pragma unroll
    for (int qq = 0; qq < 2; qq++)
      #pragma unroll
      for (int r = 0; r < 4; r++)
        red[wave][qq * 16 + g * 4 + r] = 1.0f / lpart[qq][r];
  }
  __syncthreads();
  #pragma unroll
  for (int qq = 0; qq < 2; qq++) {
    const float linv = red[wave][qq * 16 + c];
    unsigned short* yp =
        Y + (tokbase + qbase + qw + qq * 16 + c) * DIMC + col0;
    #pragma unroll
    for (int dt = 0; dt < 8; dt++)
      #pragma unroll
      for (int r = 0; r < 4; r++)
        yp[dt * 16 + g * 4 + r] = f2b(od[dt][qq][r] * linv);
  }
}

extern "C" void kernel_launch(void* const* d_in, const int* in_sizes, int n_in,
                              void* d_out, int out_size, void* d_ws, size_t ws_size,
                              hipStream_t stream)
{
  const void* x  = d_in[0];
  const void* wq = d_in[1];
  const void* wk = d_in[2];
  const void* wv = d_in[3];
  const void* wo = d_in[4];
  float* out = (float*)d_out;

  char* ws = (char*)d_ws;
  const size_t MB = 1024 * 1024;
  unsigned short* wbuf = (unsigned short*)(ws + 0 * MB);   // 24 MB (QKV stacked)
  unsigned short* xb   = (unsigned short*)(ws + 24 * MB);  // 16 MB
  unsigned short* Qb   = (unsigned short*)(ws + 40 * MB);  // 16 MB
  unsigned short* Kb   = (unsigned short*)(ws + 56 * MB);  // 16 MB
  unsigned short* Vb   = (unsigned short*)(ws + 72 * MB);  // 16 MB
  unsigned short* wob  = (unsigned short*)(ws + 88 * MB);  // 8 MB (if room)
  unsigned short* Yb   = xb;   // x dead after QKV projection; alias.

  // wo dequant folds into prep (one fewer dispatch) only when ws can hold
  // a separate 8 MB wo buffer; else fall back to the post-fattn dequant
  // overwriting wbuf's (by then dead) wq slab.
  const int wo_in_prep = (ws_size >= 97 * MB) ? 1 : 0;

  prep<<<dim3(8192, wo_in_prep ? 5 : 4), 256, 0, stream>>>(
      x, wq, wk, wv, wo, xb, wbuf, wob);
  gemm_qkv<<<dim3(48, 32), 256, 0, stream>>>(xb, wbuf, Qb, Kb, Vb, DIMC);
  rope_kernel<<<dim3(16384), 256, 0, stream>>>(Qb, Kb);
  fattn<<<dim3(512), 256, 0, stream>>>(Qb, Kb, Vb, Yb);
  const unsigned short* wo_b;
  if (wo_in_prep) {
    wo_b = wob;
  } else {
    dequant_auto<<<dim3(8192), 256, 0, stream>>>(wo, x, wbuf);
    wo_b = wbuf;
  }
  gemm_bt<float><<<dim3(16, 32), 256, 0, stream>>>(Yb, wo_b, out, NTOK, DIMC, DIMC);
}

// Round 5
// 410.428 us; speedup vs baseline: 1.0079x; 1.0079x over previous
//
#include <hip/hip_runtime.h>
#include <stdint.h>
#include <math.h>

#define DIMC 2048
#define NHEADS 16
#define HDIM 128
#define TSEQ 2048
#define NTOK 4096   // B*T

using bf16x8 = __attribute__((ext_vector_type(8))) short;
using f32x4  = __attribute__((ext_vector_type(4))) float;

typedef __attribute__((address_space(1))) const void gas_void;
typedef __attribute__((address_space(3))) void las_void;

static __device__ __forceinline__ unsigned short f2b(float f) {
  union { float f; unsigned int u; } a; a.f = f;
  unsigned int u = a.u;
  u = (u + 0x7fffu + ((u >> 16) & 1u)) >> 16;   // RNE
  return (unsigned short)u;
}
static __device__ __forceinline__ float b2f(unsigned short s) {
  union { unsigned int u; float f; } a; a.u = ((unsigned int)s) << 16;
  return a.f;
}

// wave-uniform input dtype detect (bf16 vs fp32) from x's first 128 shorts.
// 256B read is L2-broadcast after the first block; replaces the detect
// kernel + flag round-trip (dispatch-count reduction).
static __device__ __forceinline__ int detect_inline(const void* __restrict__ x)
{
  const int lane = threadIdx.x & 63;
  const unsigned short u = ((const unsigned short*)x)[2 * lane];
  const int e = (u >> 7) & 0xFF;
  const unsigned long long m = __ballot((e >= 112) && (e <= 135));
  return (__popcll(m) >= 32) ? 1 : 0;
}

// ---------------- ternary dequant core (dtype-flag branched) --------------
static __device__ __forceinline__ void dequant_one(
    const void* __restrict__ w, unsigned short* __restrict__ o,
    int grp, int lane, int isbf16)
{
  float a, bq;
  if (isbf16) {
    const unsigned int pk =
        ((const unsigned int*)((const unsigned short*)w + (long)grp * 128))[lane];
    a  = b2f((unsigned short)(pk & 0xffffu));
    bq = b2f((unsigned short)(pk >> 16));
  } else {
    const float2 v = ((const float2*)((const float*)w + (long)grp * 128))[lane];
    a = v.x; bq = v.y;
  }
  double s = fabs((double)a) + fabs((double)bq);
  #pragma unroll
  for (int off = 1; off < 64; off <<= 1) s += __shfl_xor(s, off);
  double scale = s * (1.0 / 128.0);
  if (scale < 1e-8) scale = 1e-8;
  const float fs = (float)scale;
  const double wn0 = (double)a / scale;
  const double wn1 = (double)bq / scale;
  const float q0 = (wn0 > 0.5) ? fs : ((wn0 < -0.5) ? -fs : 0.0f);
  const float q1 = (wn1 > 0.5) ? fs : ((wn1 < -0.5) ? -fs : 0.0f);
  const unsigned int opk = (unsigned int)f2b(q0) | ((unsigned int)f2b(q1) << 16);
  ((unsigned int*)o)[(long)grp * 64 + lane] = opk;
}

// fused prep: y=0 cast x->bf16; y=1..3 dequant wq/wk/wv into row-stacked
// [6144][2048]; y=4 (only when ws has room) dequant wo into its own buffer.
__global__ void __launch_bounds__(256) prep(
    const void* __restrict__ x,
    const void* __restrict__ w0, const void* __restrict__ w1,
    const void* __restrict__ w2, const void* __restrict__ w3,
    unsigned short* __restrict__ xb, unsigned short* __restrict__ wqkv,
    unsigned short* __restrict__ wob)
{
  const int isbf16 = detect_inline(x);
  const int wave = threadIdx.x >> 6, lane = threadIdx.x & 63;
  const int y = blockIdx.y;
  if (y == 0) {
    const int i = (blockIdx.x * 256 + threadIdx.x) * 4;
    if (isbf16) {
      *(ushort4*)(xb + i) = *(const ushort4*)((const unsigned short*)x + i);
    } else {
      const float4 v = *(const float4*)((const float*)x + i);
      ushort4 u;
      u.x = f2b(v.x); u.y = f2b(v.y); u.z = f2b(v.z); u.w = f2b(v.w);
      *(ushort4*)(xb + i) = u;
    }
  } else if (y <= 3) {
    const void* w = (y == 1) ? w0 : (y == 2) ? w1 : w2;
    dequant_one(w, wqkv + (long)(y - 1) * DIMC * DIMC,
                blockIdx.x * 4 + wave, lane, isbf16);
  } else {
    dequant_one(w3, wob, blockIdx.x * 4 + wave, lane, isbf16);
  }
}

// fallback wo-dequant (inline flag) when ws can't host a separate wo buffer
__global__ void __launch_bounds__(256) dequant_auto(
    const void* __restrict__ w, const void* __restrict__ x,
    unsigned short* __restrict__ o)
{
  const int isbf16 = detect_inline(x);
  dequant_one(w, o, blockIdx.x * 4 + (threadIdx.x >> 6), threadIdx.x & 63,
              isbf16);
}

// ---------------- bf16 GEMM, C[m,n] = sum_k A[m,k]*B[n,k] (B^T input) -----
// BK=64 variant of the m97 structure: 128x128 tile. Proven 123-124 us for
// QKV; the 256^2 8-phase port measured SLOWER (129 us: 1.5-round grid
// quantization at 1 block/CU + unhidden stalls at 2 waves/SIMD) — keep
// multi-block TLP latency hiding instead.
__device__ __forceinline__ void storeOne(float* C, long i, float v) { C[i] = v; }
__device__ __forceinline__ void storeOne(unsigned short* C, long i, float v) { C[i] = f2b(v); }

template <typename OUTT>
static __device__ __forceinline__ void gemm_tile(
    const unsigned short* __restrict__ A, const unsigned short* __restrict__ B,
    OUTT* __restrict__ C, int m0, int n0, int Nc, int K,
    unsigned short* As, unsigned short* Bs)   // each 128*64 elems (2 half-panels)
{
  const int tid = threadIdx.x;
  const int wave = tid >> 6;
  const int lane = tid & 63;
  const int wr = (wave >> 1) * 64, wc = (wave & 1) * 64;
  const int c16 = lane & 15, q4 = lane >> 4;

  f32x4 acc[4][4];
  #pragma unroll
  for (int i = 0; i < 4; i++)
    #pragma unroll
    for (int j = 0; j < 4; j++)
      acc[i][j] = (f32x4){0.f, 0.f, 0.f, 0.f};

  const int srow = tid >> 2;            // 0..63
  const int scol = (tid & 3) * 8;       // 16 B chunk within a 32-col half
  const unsigned short* ga = A + (long)(m0 + srow) * K + scol;
  const unsigned short* gb = B + (long)(n0 + srow) * K + scol;

  for (int k0 = 0; k0 < K; k0 += 64) {
    #pragma unroll
    for (int h = 0; h < 2; h++)             // k-half: cols k0+h*32
      #pragma unroll
      for (int i = 0; i < 2; i++) {         // row-half: rows i*64
        __builtin_amdgcn_global_load_lds(
            (gas_void*)(ga + (long)i * 64 * K + k0 + h * 32),
            (las_void*)(As + h * 4096 + i * 2048 + wave * 512), 16, 0, 0);
        __builtin_amdgcn_global_load_lds(
            (gas_void*)(gb + (long)i * 64 * K + k0 + h * 32),
            (las_void*)(Bs + h * 4096 + i * 2048 + wave * 512), 16, 0, 0);
      }
    __syncthreads();
    #pragma unroll
    for (int kc = 0; kc < 2; kc++) {
      bf16x8 af[4], bfr[4];
      #pragma unroll
      for (int t = 0; t < 4; t++) {
        af[t]  = *(const bf16x8*)(As + kc * 4096 + (wr + t * 16 + c16) * 32 + q4 * 8);
        bfr[t] = *(const bf16x8*)(Bs + kc * 4096 + (wc + t * 16 + c16) * 32 + q4 * 8);
      }
      #pragma unroll
      for (int mt = 0; mt < 4; mt++)
        #pragma unroll
        for (int nt = 0; nt < 4; nt++)
          acc[mt][nt] = __builtin_amdgcn_mfma_f32_16x16x32_bf16(af[mt], bfr[nt], acc[mt][nt], 0, 0, 0);
    }
    __syncthreads();
  }

  // C/D layout (m89-verified): n = lane&15, m = (lane>>4)*4 + reg
  #pragma unroll
  for (int mt = 0; mt < 4; mt++) {
    const int m = m0 + wr + mt * 16 + q4 * 4;
    #pragma unroll
    for (int nt = 0; nt < 4; nt++) {
      const int n = wc + nt * 16 + c16;   // caller pre-offsets C to its n0
      #pragma unroll
      for (int r = 0; r < 4; r++)
        storeOne(C, (long)(m + r) * Nc + n, acc[mt][nt][r]);
    }
  }
}

template <typename OUTT>
__global__ void __launch_bounds__(256) gemm_bt(
    const unsigned short* __restrict__ A, const unsigned short* __restrict__ B,
    OUTT* __restrict__ C, int M, int N, int K)
{
  __shared__ unsigned short As[128 * 64];
  __shared__ unsigned short Bs[128 * 64];
  gemm_tile<OUTT>(A, B, C + blockIdx.x * 128, blockIdx.y * 128, blockIdx.x * 128,
                  N, K, As, Bs);
}

// fused QKV: B row-stacked [6144][2048]; 128-col slab routed per buffer
__global__ void __launch_bounds__(256) gemm_qkv(
    const unsigned short* __restrict__ A, const unsigned short* __restrict__ B,
    unsigned short* __restrict__ C0, unsigned short* __restrict__ C1,
    unsigned short* __restrict__ C2, int K)
{
  __shared__ unsigned short As[128 * 64];
  __shared__ unsigned short Bs[128 * 64];
  const int n0 = blockIdx.x * 128;                 // 0..6143
  unsigned short* Cb = (n0 < 2048) ? C0 : (n0 < 4096) ? C1 : C2;
  gemm_tile<unsigned short>(A, B, Cb + (n0 & 2047), blockIdx.y * 128, n0,
                            DIMC, K, As, Bs);
}

// ---------------- RoPE in-place on Q and K (bf16), 4 d/thread ------------
// Vectorized: ushort4 (8B/lane) loads/stores instead of scalar 2B; 1.05M
// threads instead of 4.2M. Bit-exact: identical expf/sincosf per element.
__global__ void __launch_bounds__(256) rope_kernel(
    unsigned short* __restrict__ Q, unsigned short* __restrict__ Kb)
{
  const int idx = blockIdx.x * 256 + threadIdx.x;   // 0..1048575
  const int d4 = (idx & 15) * 4;                    // 0,4,..,60
  const int h = (idx >> 4) & (NHEADS - 1);
  const int row = idx >> 8;                         // 0..4095
  const int t = row & (TSEQ - 1);
  const long base = (long)row * DIMC + h * HDIM + d4;

  ushort4 q1 = *(ushort4*)(Q + base), q2 = *(ushort4*)(Q + base + 64);
  ushort4 k1 = *(ushort4*)(Kb + base), k2 = *(ushort4*)(Kb + base + 64);
  unsigned short* q1p = (unsigned short*)&q1;
  unsigned short* q2p = (unsigned short*)&q2;
  unsigned short* k1p = (unsigned short*)&k1;
  unsigned short* k2p = (unsigned short*)&k2;

  #pragma unroll
  for (int j = 0; j < 4; j++) {
    const int d = d4 + j;
    const float inv_freq = expf(-9.210340371976184f * (float)d * (1.0f / 64.0f));
    float sn, cs;
    sincosf((float)t * inv_freq, &sn, &cs);
    float x1 = b2f(q1p[j]), x2 = b2f(q2p[j]);
    q1p[j] = f2b(x1 * cs - x2 * sn);
    q2p[j] = f2b(x1 * sn + x2 * cs);
    x1 = b2f(k1p[j]); x2 = b2f(k2p[j]);
    k1p[j] = f2b(x1 * cs - x2 * sn);
    k2p[j] = f2b(x1 * sn + x2 * cs);
  }
  *(ushort4*)(Q + base) = q1;  *(ushort4*)(Q + base + 64) = q2;
  *(ushort4*)(Kb + base) = k1; *(ushort4*)(Kb + base + 64) = k2;
}

// ---------------- flash attention v3 (causal), bf16 MFMA ----------------
// EXACT round-0 version (best-measured state). Both later variants
// regressed ~+10us: raw-barrier+setprio (R2: setprio is the lockstep-
// negative m190 regime here) and XOR-swizzle (R3: the padded 136-short
// stride is 17 slots = co-prime with 8, so the old layout was ALREADY at
// the b128 minimum of 8 lanes/slot — swizzle only added address VALU).
#define FA_M 16.0f
__global__ void __launch_bounds__(256) fattn(
    const unsigned short* __restrict__ Q,
    const unsigned short* __restrict__ K,
    const unsigned short* __restrict__ V,
    unsigned short* __restrict__ Y)
{
  __shared__ unsigned short SU[9216];       // 18432 B union (Ks | Ps)
  __shared__ unsigned short VT[128 * 72];   // 18432 B
  __shared__ float red[4][32];

  const int tid = threadIdx.x, wave = tid >> 6, lane = tid & 63;
  const int idx = blockIdx.x;               // 512 blocks
  const int qt = 15 - (idx >> 5);           // heaviest (qt=15) first
  const int bh = idx & 31;
  const int b = bh >> 4, h = bh & 15;
  const int qbase = qt * 128;
  const int qw = wave * 32;
  const int c = lane & 15, g = lane >> 4;
  const long tokbase = (long)b * TSEQ;
  const int col0 = h * HDIM;

  bf16x8 qf[2][4];
  #pragma unroll
  for (int qq = 0; qq < 2; qq++) {
    const unsigned short* qp =
        Q + (tokbase + qbase + qw + qq * 16 + c) * DIMC + col0 + g * 8;
    #pragma unroll
    for (int kc = 0; kc < 4; kc++) qf[qq][kc] = *(const bf16x8*)(qp + kc * 32);
  }

  f32x4 od[8][2];
  #pragma unroll
  for (int dt = 0; dt < 8; dt++)
    #pragma unroll
    for (int qq = 0; qq < 2; qq++)
      od[dt][qq] = (f32x4){0.f, 0.f, 0.f, 0.f};
  float lpart[2][4];
  #pragma unroll
  for (int qq = 0; qq < 2; qq++)
    #pragma unroll
    for (int r = 0; r < 4; r++) lpart[qq][r] = 0.0f;

  const int ksr = tid >> 2, ksc = (tid & 3) * 32;
  const int vk0 = (tid & 31) * 2, vd0 = (tid >> 5) * 16;

  const float SC = 0.088388347648318447f;  // 1/sqrt(128)
  const int nkt = 2 * qt + 2;

  // prefetch registers (K row chunk: 4x float4; V: 2 keys x 16 d)
  float4 kr0, kr1, kr2, kr3;
  bf16x8 va0, va1, vb0, vb1;
  {
    const unsigned short* src = K + (tokbase + ksr) * DIMC + col0 + ksc;
    kr0 = ((const float4*)src)[0]; kr1 = ((const float4*)src)[1];
    kr2 = ((const float4*)src)[2]; kr3 = ((const float4*)src)[3];
    const unsigned short* s0 = V + (tokbase + vk0) * DIMC + col0 + vd0;
    const unsigned short* s1 = s0 + DIMC;
    va0 = *(const bf16x8*)(s0); va1 = *(const bf16x8*)(s0 + 8);
    vb0 = *(const bf16x8*)(s1); vb1 = *(const bf16x8*)(s1 + 8);
  }

  for (int kt = 0; kt < nkt; kt++) {
    const int kb = kt * 64;
    __syncthreads();   // A: prev-iter readers done with SU/VT
    {
      float4* dst = (float4*)&SU[ksr * 136 + ksc];
      dst[0] = kr0; dst[1] = kr1; dst[2] = kr2; dst[3] = kr3;
    }
    {
      #pragma unroll
      for (int dd = 0; dd < 8; dd++) {
        const unsigned int p0 =
            (unsigned int)(unsigned short)va0[dd] |
            ((unsigned int)(unsigned short)vb0[dd] << 16);
        *(unsigned int*)&VT[(vd0 + dd) * 72 + vk0] = p0;
      }
      #pragma unroll
      for (int dd = 0; dd < 8; dd++) {
        const unsigned int p1 =
            (unsigned int)(unsigned short)va1[dd] |
            ((unsigned int)(unsigned short)vb1[dd] << 16);
        *(unsigned int*)&VT[(vd0 + 8 + dd) * 72 + vk0] = p1;
      }
    }
    __syncthreads();   // B: staging visible

    if (kt + 1 < nkt) {   // issue next tile's loads; consumed at next barrier A
      const int kb2 = kb + 64;
      const unsigned short* src = K + (tokbase + kb2 + ksr) * DIMC + col0 + ksc;
      kr0 = ((const float4*)src)[0]; kr1 = ((const float4*)src)[1];
      kr2 = ((const float4*)src)[2]; kr3 = ((const float4*)src)[3];
      const unsigned short* s0 = V + (tokbase + kb2 + vk0) * DIMC + col0 + vd0;
      const unsigned short* s1 = s0 + DIMC;
      va0 = *(const bf16x8*)(s0); va1 = *(const bf16x8*)(s0 + 8);
      vb0 = *(const bf16x8*)(s1); vb1 = *(const bf16x8*)(s1 + 8);
    }

    f32x4 sacc[2][4];
    #pragma unroll
    for (int qq = 0; qq < 2; qq++)
      #pragma unroll
      for (int nt = 0; nt < 4; nt++) sacc[qq][nt] = (f32x4){0.f, 0.f, 0.f, 0.f};
    #pragma unroll
    for (int kc = 0; kc < 4; kc++) {
      bf16x8 bk[4];
      #pragma unroll
      for (int nt = 0; nt < 4; nt++)
        bk[nt] = *(const bf16x8*)&SU[(nt * 16 + c) * 136 + kc * 32 + g * 8];
      #pragma unroll
      for (int qq = 0; qq < 2; qq++)
        #pragma unroll
        for (int nt = 0; nt < 4; nt++)
          sacc[qq][nt] = __builtin_amdgcn_mfma_f32_16x16x32_bf16(
              qf[qq][kc], bk[nt], sacc[qq][nt], 0, 0, 0);
    }
    __syncthreads();   // C: Ks reads done before Ps overwrites SU

    #pragma unroll
    for (int qq = 0; qq < 2; qq++)
      #pragma unroll
      for (int r = 0; r < 4; r++) {
        const int qg = qbase + qw + qq * 16 + g * 4 + r;
        #pragma unroll
        for (int nt = 0; nt < 4; nt++) {
          const int kg = kb + nt * 16 + c;
          const float sv = sacc[qq][nt][r] * SC - FA_M;
          const float p = (kg > qg) ? 0.0f : __expf(sv);
          lpart[qq][r] += p;
          SU[(wave * 32 + qq * 16 + g * 4 + r) * 72 + nt * 16 + c] = f2b(p);
        }
      }

    #pragma unroll
    for (int kc = 0; kc < 2; kc++) {
      bf16x8 pb[2];
      #pragma unroll
      for (int qq = 0; qq < 2; qq++)
        pb[qq] = *(const bf16x8*)&SU[(wave * 32 + qq * 16 + c) * 72 + kc * 32 + g * 8];
      #pragma unroll
      for (int dt = 0; dt < 8; dt++) {
        bf16x8 va = *(const bf16x8*)&VT[(dt * 16 + c) * 72 + kc * 32 + g * 8];
        #pragma unroll
        for (int qq = 0; qq < 2; qq++)
          od[dt][qq] = __builtin_amdgcn_mfma_f32_16x16x32_bf16(
              va, pb[qq], od[dt][qq], 0, 0, 0);
      }
    }
  }

  #pragma unroll
  for (int qq = 0; qq < 2; qq++)
    #pragma unroll
    for (int r = 0; r < 4; r++) {
      float l = lpart[qq][r];
      #pragma unroll
      for (int off = 1; off < 16; off <<= 1) l += __shfl_xor(l, off);
      lpart[qq][r] = l;
    }
  __syncthreads();
  if (c == 0) {
    #pragma unroll
    for (int qq = 0; qq < 2; qq++)
      #pragma unroll
      for (int r = 0; r < 4; r++)
        red[wave][qq * 16 + g * 4 + r] = 1.0f / lpart[qq][r];
  }
  __syncthreads();
  #pragma unroll
  for (int qq = 0; qq < 2; qq++) {
    const float linv = red[wave][qq * 16 + c];
    unsigned short* yp =
        Y + (tokbase + qbase + qw + qq * 16 + c) * DIMC + col0;
    #pragma unroll
    for (int dt = 0; dt < 8; dt++)
      #pragma unroll
      for (int r = 0; r < 4; r++)
        yp[dt * 16 + g * 4 + r] = f2b(od[dt][qq][r] * linv);
  }
}

extern "C" void kernel_launch(void* const* d_in, const int* in_sizes, int n_in,
                              void* d_out, int out_size, void* d_ws, size_t ws_size,
                              hipStream_t stream)
{
  const void* x  = d_in[0];
  const void* wq = d_in[1];
  const void* wk = d_in[2];
  const void* wv = d_in[3];
  const void* wo = d_in[4];
  float* out = (float*)d_out;

  char* ws = (char*)d_ws;
  const size_t MB = 1024 * 1024;
  unsigned short* wbuf = (unsigned short*)(ws + 0 * MB);   // 24 MB (QKV stacked)
  unsigned short* xb   = (unsigned short*)(ws + 24 * MB);  // 16 MB
  unsigned short* Qb   = (unsigned short*)(ws + 40 * MB);  // 16 MB
  unsigned short* Kb   = (unsigned short*)(ws + 56 * MB);  // 16 MB
  unsigned short* Vb   = (unsigned short*)(ws + 72 * MB);  // 16 MB
  unsigned short* wob  = (unsigned short*)(ws + 88 * MB);  // 8 MB (if room)
  unsigned short* Yb   = xb;   // x dead after QKV projection; alias.

  // wo dequant folds into prep (one fewer dispatch) only when ws can hold
  // a separate 8 MB wo buffer; else fall back to the post-fattn dequant
  // overwriting wbuf's (by then dead) wq slab.
  const int wo_in_prep = (ws_size >= 97 * MB) ? 1 : 0;

  prep<<<dim3(8192, wo_in_prep ? 5 : 4), 256, 0, stream>>>(
      x, wq, wk, wv, wo, xb, wbuf, wob);
  gemm_qkv<<<dim3(48, 32), 256, 0, stream>>>(xb, wbuf, Qb, Kb, Vb, DIMC);
  rope_kernel<<<dim3(4096), 256, 0, stream>>>(Qb, Kb);
  fattn<<<dim3(512), 256, 0, stream>>>(Qb, Kb, Vb, Yb);
  const unsigned short* wo_b;
  if (wo_in_prep) {
    wo_b = wob;
  } else {
    dequant_auto<<<dim3(8192), 256, 0, stream>>>(wo, x, wbuf);
    wo_b = wbuf;
  }
  gemm_bt<float><<<dim3(16, 32), 256, 0, stream>>>(Yb, wo_b, out, NTOK, DIMC, DIMC);
}

// Round 6
// 391.685 us; speedup vs baseline: 1.0561x; 1.0479x over previous
//
#include <hip/hip_runtime.h>
#include <stdint.h>
#include <math.h>

#define DIMC 2048
#define NHEADS 16
#define HDIM 128
#define TSEQ 2048
#define NTOK 4096   // B*T

using bf16x8 = __attribute__((ext_vector_type(8))) short;
using f32x4  = __attribute__((ext_vector_type(4))) float;

typedef __attribute__((address_space(1))) const void gas_void;
typedef __attribute__((address_space(3))) void las_void;

static __device__ __forceinline__ unsigned short f2b(float f) {
  union { float f; unsigned int u; } a; a.f = f;
  unsigned int u = a.u;
  u = (u + 0x7fffu + ((u >> 16) & 1u)) >> 16;   // RNE
  return (unsigned short)u;
}
static __device__ __forceinline__ float b2f(unsigned short s) {
  union { unsigned int u; float f; } a; a.u = ((unsigned int)s) << 16;
  return a.f;
}

// wave-uniform input dtype detect (bf16 vs fp32) from x's first 128 shorts.
static __device__ __forceinline__ int detect_inline(const void* __restrict__ x)
{
  const int lane = threadIdx.x & 63;
  const unsigned short u = ((const unsigned short*)x)[2 * lane];
  const int e = (u >> 7) & 0xFF;
  const unsigned long long m = __ballot((e >= 112) && (e <= 135));
  return (__popcll(m) >= 32) ? 1 : 0;
}

// ---------------- ternary dequant core (dtype-flag branched) --------------
static __device__ __forceinline__ void dequant_one(
    const void* __restrict__ w, unsigned short* __restrict__ o,
    int grp, int lane, int isbf16)
{
  float a, bq;
  if (isbf16) {
    const unsigned int pk =
        ((const unsigned int*)((const unsigned short*)w + (long)grp * 128))[lane];
    a  = b2f((unsigned short)(pk & 0xffffu));
    bq = b2f((unsigned short)(pk >> 16));
  } else {
    const float2 v = ((const float2*)((const float*)w + (long)grp * 128))[lane];
    a = v.x; bq = v.y;
  }
  double s = fabs((double)a) + fabs((double)bq);
  #pragma unroll
  for (int off = 1; off < 64; off <<= 1) s += __shfl_xor(s, off);
  double scale = s * (1.0 / 128.0);
  if (scale < 1e-8) scale = 1e-8;
  const float fs = (float)scale;
  const double wn0 = (double)a / scale;
  const double wn1 = (double)bq / scale;
  const float q0 = (wn0 > 0.5) ? fs : ((wn0 < -0.5) ? -fs : 0.0f);
  const float q1 = (wn1 > 0.5) ? fs : ((wn1 < -0.5) ? -fs : 0.0f);
  const unsigned int opk = (unsigned int)f2b(q0) | ((unsigned int)f2b(q1) << 16);
  ((unsigned int*)o)[(long)grp * 64 + lane] = opk;
}

// fused prep: y=0 cast x->bf16; y=1..3 dequant wq/wk/wv into row-stacked
// [6144][2048]; y=4 (only when ws has room) dequant wo into its own buffer.
__global__ void __launch_bounds__(256) prep(
    const void* __restrict__ x,
    const void* __restrict__ w0, const void* __restrict__ w1,
    const void* __restrict__ w2, const void* __restrict__ w3,
    unsigned short* __restrict__ xb, unsigned short* __restrict__ wqkv,
    unsigned short* __restrict__ wob)
{
  const int isbf16 = detect_inline(x);
  const int wave = threadIdx.x >> 6, lane = threadIdx.x & 63;
  const int y = blockIdx.y;
  if (y == 0) {
    const int i = (blockIdx.x * 256 + threadIdx.x) * 4;
    if (isbf16) {
      *(ushort4*)(xb + i) = *(const ushort4*)((const unsigned short*)x + i);
    } else {
      const float4 v = *(const float4*)((const float*)x + i);
      ushort4 u;
      u.x = f2b(v.x); u.y = f2b(v.y); u.z = f2b(v.z); u.w = f2b(v.w);
      *(ushort4*)(xb + i) = u;
    }
  } else if (y <= 3) {
    const void* w = (y == 1) ? w0 : (y == 2) ? w1 : w2;
    dequant_one(w, wqkv + (long)(y - 1) * DIMC * DIMC,
                blockIdx.x * 4 + wave, lane, isbf16);
  } else {
    dequant_one(w3, wob, blockIdx.x * 4 + wave, lane, isbf16);
  }
}

// fallback wo-dequant (inline flag) when ws can't host a separate wo buffer
__global__ void __launch_bounds__(256) dequant_auto(
    const void* __restrict__ w, const void* __restrict__ x,
    unsigned short* __restrict__ o)
{
  const int isbf16 = detect_inline(x);
  dequant_one(w, o, blockIdx.x * 4 + (threadIdx.x >> 6), threadIdx.x & 63,
              isbf16);
}

// ========== 256x128-tile 8-wave 2-phase-per-K GEMM (swizzled LDS) =========
// C[m,n] = sum_k A[m,k]*B[n,k]. Derived from the R1 refcheck-passed 256^2
// 8-phase kernel (identical subtile/swizzle/stage formulas) with BN 256->128:
//   QKV grid 48x16 = 768 blocks = EXACTLY 3.0 rounds at 1 block/CU (R1's 384
//   blocks = 1.5 rounds wasted 25% CU-time; per-round rate measured 1067 TF).
//   wo grid 16x16 = 256 = exactly 1.0 round.
// LDS 96KB: sm[dbuf2][A-half0|A-half1|B][8192 shorts], each 128rx64c as 16
// st_16x32-swizzled 512-short subtiles; global_load_lds writes linear with
// inverse-swizzled SOURCE addr; ds_reads apply the swizzle (both-sides rule).
// Per K-tile t:
//  ph1: 16 ds_reads (af all-m, b01, b23) | stage A(t+1)->nxt (4 loads)
//       | BAR | lgkm0 | 16 MFMA (n0-1) | BAR
//  ph2: stage B(t+2)->sm[cur][B] (safe: all B-reads retired at ph1-end BAR
//       via each wave's lgkmcnt(0)) | 16 MFMA (n2-3) | vmcnt(2) | BAR
// vmcnt ledger at ph2-end: outstanding = {B(t+1), A0(t+1), A1(t+1), B(t+2)}
// = 8 instrs -> vmcnt(2) keeps only B(t+2) in flight (full-iter slack);
// never drains to 0 mid-loop.
static __device__ __forceinline__ void gemm8_core(
    const unsigned short* __restrict__ A, const unsigned short* __restrict__ Bm,
    int m0, int n0, int K, f32x4 (&acc)[4][4],
    unsigned short (*sm)[3][8192])
{
  const int tid = threadIdx.x;
  const int w = tid >> 6, lane = tid & 63;
  const int wr = w >> 1, wc = w & 1;
  const int c16 = lane & 15, q4 = lane >> 4;
  const int swz = (c16 * 32 + q4 * 8) ^ ((c16 & 8) ? 16 : 0);
  const int srow = lane >> 2;
  const int scol = ((lane & 3) * 8) ^ ((lane & 32) ? 16 : 0);
  const int rg0 = w >> 1, cg = w & 1;
  const int NT = K >> 6;

  #pragma unroll
  for (int i = 0; i < 4; i++)
    #pragma unroll
    for (int j = 0; j < 4; j++) acc[i][j] = (f32x4){0.f, 0.f, 0.f, 0.f};

  auto stage = [&](const unsigned short* __restrict__ G, int rowbase, int kt,
                   unsigned short* dst) {
    #pragma unroll
    for (int l = 0; l < 2; l++) {
      const unsigned short* s = G +
          (long)(rowbase + (rg0 + l * 4) * 16 + srow) * K + kt * 64 + cg * 32 + scol;
      __builtin_amdgcn_global_load_lds((gas_void*)s,
          (las_void*)(dst + (l * 8 + w) * 512), 16, 0, 0);
    }
  };

  // prologue: t0 {A0,A1,B} -> parity0 ; B(1) -> parity1
  stage(A,  m0,       0, sm[0][0]);
  stage(A,  m0 + 128, 0, sm[0][1]);
  stage(Bm, n0,       0, sm[0][2]);
  stage(Bm, n0,       1, sm[1][2]);
  asm volatile("s_waitcnt vmcnt(2)" ::: "memory");
  __builtin_amdgcn_s_barrier();

  bf16x8 af[4][2], b01[2][2], b23[2][2];
  const int ah = wr >> 1;               // which A half (0: rows<128)
  const int abase = (wr & 1) * 4096;    // 4 subtiles into that half
  const int bbase = wc * 4096;          // B cols wc*64

  for (int t = 0; t < NT; ++t) {
    const int cur = t & 1, nxt = cur ^ 1;

    // -------- phase 1 --------
    #pragma unroll
    for (int m = 0; m < 4; m++)
      #pragma unroll
      for (int kk = 0; kk < 2; kk++)
        af[m][kk] = *(const bf16x8*)&sm[cur][ah][abase + m * 1024 + kk * 512 + swz];
    #pragma unroll
    for (int n = 0; n < 2; n++)
      #pragma unroll
      for (int kk = 0; kk < 2; kk++) {
        b01[n][kk] = *(const bf16x8*)&sm[cur][2][bbase + n * 1024 + kk * 512 + swz];
        b23[n][kk] = *(const bf16x8*)&sm[cur][2][bbase + (2 + n) * 1024 + kk * 512 + swz];
      }
    if (t + 1 < NT) {
      stage(A, m0,       t + 1, sm[nxt][0]);
      stage(A, m0 + 128, t + 1, sm[nxt][1]);
    }
    __builtin_amdgcn_s_barrier();
    asm volatile("s_waitcnt lgkmcnt(0)" ::: "memory");
    __builtin_amdgcn_s_setprio(1);
    #pragma unroll
    for (int kk = 0; kk < 2; kk++)
      #pragma unroll
      for (int m = 0; m < 4; m++)
        #pragma unroll
        for (int n = 0; n < 2; n++)
          acc[m][n] = __builtin_amdgcn_mfma_f32_16x16x32_bf16(
              af[m][kk], b01[n][kk], acc[m][n], 0, 0, 0);
    __builtin_amdgcn_s_setprio(0);
    __builtin_amdgcn_s_barrier();

    // -------- phase 2 --------
    if (t + 2 < NT) stage(Bm, n0, t + 2, sm[cur][2]);
    __builtin_amdgcn_s_setprio(1);
    #pragma unroll
    for (int kk = 0; kk < 2; kk++)
      #pragma unroll
      for (int m = 0; m < 4; m++)
        #pragma unroll
        for (int n = 0; n < 2; n++)
          acc[m][2 + n] = __builtin_amdgcn_mfma_f32_16x16x32_bf16(
              af[m][kk], b23[n][kk], acc[m][2 + n], 0, 0, 0);
    __builtin_amdgcn_s_setprio(0);
    if (t + 1 < NT) {
      if (t + 2 < NT) { asm volatile("s_waitcnt vmcnt(2)" ::: "memory"); }
      else            { asm volatile("s_waitcnt vmcnt(0)" ::: "memory"); }
      __builtin_amdgcn_s_barrier();
    }
  }
}

// QKV: B row-stacked [6144][2048]; 128-col slab routed per output buffer
__global__ void __launch_bounds__(512, 2) gemm8_qkv(
    const unsigned short* __restrict__ A, const unsigned short* __restrict__ Bm,
    unsigned short* __restrict__ C0, unsigned short* __restrict__ C1,
    unsigned short* __restrict__ C2, int K)
{
  __shared__ unsigned short sm[2][3][8192];   // 96 KB
  const int n0 = blockIdx.x * 128;            // 0..6143
  const int m0 = blockIdx.y * 256;
  f32x4 acc[4][4];
  gemm8_core(A, Bm, m0, n0, K, acc, sm);

  unsigned short* Cb = (n0 < 2048) ? C0 : (n0 < 4096) ? C1 : C2;
  const int w = threadIdx.x >> 6, lane = threadIdx.x & 63;
  const int wr = w >> 1, wc = w & 1;
  const int c16 = lane & 15, q4 = lane >> 4;
  const int nloc = (n0 & 2047) + wc * 64;
  #pragma unroll
  for (int mt = 0; mt < 4; mt++) {
    const int m = m0 + wr * 64 + mt * 16 + q4 * 4;
    #pragma unroll
    for (int nt = 0; nt < 4; nt++) {
      const int n = nloc + nt * 16 + c16;
      #pragma unroll
      for (int r = 0; r < 4; r++)
        Cb[(long)(m + r) * DIMC + n] = f2b(acc[mt][nt][r]);
    }
  }
}

// wo projection: fp32 output, direct [4096][2048]
__global__ void __launch_bounds__(512, 2) gemm8_bt(
    const unsigned short* __restrict__ A, const unsigned short* __restrict__ Bm,
    float* __restrict__ C, int N, int K)
{
  __shared__ unsigned short sm[2][3][8192];   // 96 KB
  const int n0 = blockIdx.x * 128;
  const int m0 = blockIdx.y * 256;
  f32x4 acc[4][4];
  gemm8_core(A, Bm, m0, n0, K, acc, sm);

  const int w = threadIdx.x >> 6, lane = threadIdx.x & 63;
  const int wr = w >> 1, wc = w & 1;
  const int c16 = lane & 15, q4 = lane >> 4;
  #pragma unroll
  for (int mt = 0; mt < 4; mt++) {
    const int m = m0 + wr * 64 + mt * 16 + q4 * 4;
    #pragma unroll
    for (int nt = 0; nt < 4; nt++) {
      const int n = n0 + wc * 64 + nt * 16 + c16;
      #pragma unroll
      for (int r = 0; r < 4; r++)
        C[(long)(m + r) * N + n] = acc[mt][nt][r];
    }
  }
}

// ---------------- RoPE in-place on Q and K (bf16), 4 d/thread ------------
__global__ void __launch_bounds__(256) rope_kernel(
    unsigned short* __restrict__ Q, unsigned short* __restrict__ Kb)
{
  const int idx = blockIdx.x * 256 + threadIdx.x;   // 0..1048575
  const int d4 = (idx & 15) * 4;                    // 0,4,..,60
  const int h = (idx >> 4) & (NHEADS - 1);
  const int row = idx >> 8;                         // 0..4095
  const int t = row & (TSEQ - 1);
  const long base = (long)row * DIMC + h * HDIM + d4;

  ushort4 q1 = *(ushort4*)(Q + base), q2 = *(ushort4*)(Q + base + 64);
  ushort4 k1 = *(ushort4*)(Kb + base), k2 = *(ushort4*)(Kb + base + 64);
  unsigned short* q1p = (unsigned short*)&q1;
  unsigned short* q2p = (unsigned short*)&q2;
  unsigned short* k1p = (unsigned short*)&k1;
  unsigned short* k2p = (unsigned short*)&k2;

  #pragma unroll
  for (int j = 0; j < 4; j++) {
    const int d = d4 + j;
    const float inv_freq = expf(-9.210340371976184f * (float)d * (1.0f / 64.0f));
    float sn, cs;
    sincosf((float)t * inv_freq, &sn, &cs);
    float x1 = b2f(q1p[j]), x2 = b2f(q2p[j]);
    q1p[j] = f2b(x1 * cs - x2 * sn);
    q2p[j] = f2b(x1 * sn + x2 * cs);
    x1 = b2f(k1p[j]); x2 = b2f(k2p[j]);
    k1p[j] = f2b(x1 * cs - x2 * sn);
    k2p[j] = f2b(x1 * sn + x2 * cs);
  }
  *(ushort4*)(Q + base) = q1;  *(ushort4*)(Q + base + 64) = q2;
  *(ushort4*)(Kb + base) = k1; *(ushort4*)(Kb + base + 64) = k2;
}

// ---------------- flash attention v3 (causal), bf16 MFMA ----------------
// EXACT round-0 version (best-measured state; R2/R3 variants regressed).
#define FA_M 16.0f
__global__ void __launch_bounds__(256) fattn(
    const unsigned short* __restrict__ Q,
    const unsigned short* __restrict__ K,
    const unsigned short* __restrict__ V,
    unsigned short* __restrict__ Y)
{
  __shared__ unsigned short SU[9216];       // 18432 B union (Ks | Ps)
  __shared__ unsigned short VT[128 * 72];   // 18432 B
  __shared__ float red[4][32];

  const int tid = threadIdx.x, wave = tid >> 6, lane = tid & 63;
  const int idx = blockIdx.x;               // 512 blocks
  const int qt = 15 - (idx >> 5);           // heaviest (qt=15) first
  const int bh = idx & 31;
  const int b = bh >> 4, h = bh & 15;
  const int qbase = qt * 128;
  const int qw = wave * 32;
  const int c = lane & 15, g = lane >> 4;
  const long tokbase = (long)b * TSEQ;
  const int col0 = h * HDIM;

  bf16x8 qf[2][4];
  #pragma unroll
  for (int qq = 0; qq < 2; qq++) {
    const unsigned short* qp =
        Q + (tokbase + qbase + qw + qq * 16 + c) * DIMC + col0 + g * 8;
    #pragma unroll
    for (int kc = 0; kc < 4; kc++) qf[qq][kc] = *(const bf16x8*)(qp + kc * 32);
  }

  f32x4 od[8][2];
  #pragma unroll
  for (int dt = 0; dt < 8; dt++)
    #pragma unroll
    for (int qq = 0; qq < 2; qq++)
      od[dt][qq] = (f32x4){0.f, 0.f, 0.f, 0.f};
  float lpart[2][4];
  #pragma unroll
  for (int qq = 0; qq < 2; qq++)
    #pragma unroll
    for (int r = 0; r < 4; r++) lpart[qq][r] = 0.0f;

  const int ksr = tid >> 2, ksc = (tid & 3) * 32;
  const int vk0 = (tid & 31) * 2, vd0 = (tid >> 5) * 16;

  const float SC = 0.088388347648318447f;  // 1/sqrt(128)
  const int nkt = 2 * qt + 2;

  // prefetch registers (K row chunk: 4x float4; V: 2 keys x 16 d)
  float4 kr0, kr1, kr2, kr3;
  bf16x8 va0, va1, vb0, vb1;
  {
    const unsigned short* src = K + (tokbase + ksr) * DIMC + col0 + ksc;
    kr0 = ((const float4*)src)[0]; kr1 = ((const float4*)src)[1];
    kr2 = ((const float4*)src)[2]; kr3 = ((const float4*)src)[3];
    const unsigned short* s0 = V + (tokbase + vk0) * DIMC + col0 + vd0;
    const unsigned short* s1 = s0 + DIMC;
    va0 = *(const bf16x8*)(s0); va1 = *(const bf16x8*)(s0 + 8);
    vb0 = *(const bf16x8*)(s1); vb1 = *(const bf16x8*)(s1 + 8);
  }

  for (int kt = 0; kt < nkt; kt++) {
    const int kb = kt * 64;
    __syncthreads();   // A: prev-iter readers done with SU/VT
    {
      float4* dst = (float4*)&SU[ksr * 136 + ksc];
      dst[0] = kr0; dst[1] = kr1; dst[2] = kr2; dst[3] = kr3;
    }
    {
      #pragma unroll
      for (int dd = 0; dd < 8; dd++) {
        const unsigned int p0 =
            (unsigned int)(unsigned short)va0[dd] |
            ((unsigned int)(unsigned short)vb0[dd] << 16);
        *(unsigned int*)&VT[(vd0 + dd) * 72 + vk0] = p0;
      }
      #pragma unroll
      for (int dd = 0; dd < 8; dd++) {
        const unsigned int p1 =
            (unsigned int)(unsigned short)va1[dd] |
            ((unsigned int)(unsigned short)vb1[dd] << 16);
        *(unsigned int*)&VT[(vd0 + 8 + dd) * 72 + vk0] = p1;
      }
    }
    __syncthreads();   // B: staging visible

    if (kt + 1 < nkt) {   // issue next tile's loads; consumed at next barrier A
      const int kb2 = kb + 64;
      const unsigned short* src = K + (tokbase + kb2 + ksr) * DIMC + col0 + ksc;
      kr0 = ((const float4*)src)[0]; kr1 = ((const float4*)src)[1];
      kr2 = ((const float4*)src)[2]; kr3 = ((const float4*)src)[3];
      const unsigned short* s0 = V + (tokbase + kb2 + vk0) * DIMC + col0 + vd0;
      const unsigned short* s1 = s0 + DIMC;
      va0 = *(const bf16x8*)(s0); va1 = *(const bf16x8*)(s0 + 8);
      vb0 = *(const bf16x8*)(s1); vb1 = *(const bf16x8*)(s1 + 8);
    }

    f32x4 sacc[2][4];
    #pragma unroll
    for (int qq = 0; qq < 2; qq++)
      #pragma unroll
      for (int nt = 0; nt < 4; nt++) sacc[qq][nt] = (f32x4){0.f, 0.f, 0.f, 0.f};
    #pragma unroll
    for (int kc = 0; kc < 4; kc++) {
      bf16x8 bk[4];
      #pragma unroll
      for (int nt = 0; nt < 4; nt++)
        bk[nt] = *(const bf16x8*)&SU[(nt * 16 + c) * 136 + kc * 32 + g * 8];
      #pragma unroll
      for (int qq = 0; qq < 2; qq++)
        #pragma unroll
        for (int nt = 0; nt < 4; nt++)
          sacc[qq][nt] = __builtin_amdgcn_mfma_f32_16x16x32_bf16(
              qf[qq][kc], bk[nt], sacc[qq][nt], 0, 0, 0);
    }
    __syncthreads();   // C: Ks reads done before Ps overwrites SU

    #pragma unroll
    for (int qq = 0; qq < 2; qq++)
      #pragma unroll
      for (int r = 0; r < 4; r++) {
        const int qg = qbase + qw + qq * 16 + g * 4 + r;
        #pragma unroll
        for (int nt = 0; nt < 4; nt++) {
          const int kg = kb + nt * 16 + c;
          const float sv = sacc[qq][nt][r] * SC - FA_M;
          const float p = (kg > qg) ? 0.0f : __expf(sv);
          lpart[qq][r] += p;
          SU[(wave * 32 + qq * 16 + g * 4 + r) * 72 + nt * 16 + c] = f2b(p);
        }
      }

    #pragma unroll
    for (int kc = 0; kc < 2; kc++) {
      bf16x8 pb[2];
      #pragma unroll
      for (int qq = 0; qq < 2; qq++)
        pb[qq] = *(const bf16x8*)&SU[(wave * 32 + qq * 16 + c) * 72 + kc * 32 + g * 8];
      #pragma unroll
      for (int dt = 0; dt < 8; dt++) {
        bf16x8 va = *(const bf16x8*)&VT[(dt * 16 + c) * 72 + kc * 32 + g * 8];
        #pragma unroll
        for (int qq = 0; qq < 2; qq++)
          od[dt][qq] = __builtin_amdgcn_mfma_f32_16x16x32_bf16(
              va, pb[qq], od[dt][qq], 0, 0, 0);
      }
    }
  }

  #pragma unroll
  for (int qq = 0; qq < 2; qq++)
    #pragma unroll
    for (int r = 0; r < 4; r++) {
      float l = lpart[qq][r];
      #pragma unroll
      for (int off = 1; off < 16; off <<= 1) l += __shfl_xor(l, off);
      lpart[qq][r] = l;
    }
  __syncthreads();
  if (c == 0) {
    #pragma unroll
    for (int qq = 0; qq < 2; qq++)
      #pragma unroll
      for (int r = 0; r < 4; r++)
        red[wave][qq * 16 + g * 4 + r] = 1.0f / lpart[qq][r];
  }
  __syncthreads();
  #pragma unroll
  for (int qq = 0; qq < 2; qq++) {
    const float linv = red[wave][qq * 16 + c];
    unsigned short* yp =
        Y + (tokbase + qbase + qw + qq * 16 + c) * DIMC + col0;
    #pragma unroll
    for (int dt = 0; dt < 8; dt++)
      #pragma unroll
      for (int r = 0; r < 4; r++)
        yp[dt * 16 + g * 4 + r] = f2b(od[dt][qq][r] * linv);
  }
}

extern "C" void kernel_launch(void* const* d_in, const int* in_sizes, int n_in,
                              void* d_out, int out_size, void* d_ws, size_t ws_size,
                              hipStream_t stream)
{
  const void* x  = d_in[0];
  const void* wq = d_in[1];
  const void* wk = d_in[2];
  const void* wv = d_in[3];
  const void* wo = d_in[4];
  float* out = (float*)d_out;

  char* ws = (char*)d_ws;
  const size_t MB = 1024 * 1024;
  unsigned short* wbuf = (unsigned short*)(ws + 0 * MB);   // 24 MB (QKV stacked)
  unsigned short* xb   = (unsigned short*)(ws + 24 * MB);  // 16 MB
  unsigned short* Qb   = (unsigned short*)(ws + 40 * MB);  // 16 MB
  unsigned short* Kb   = (unsigned short*)(ws + 56 * MB);  // 16 MB
  unsigned short* Vb   = (unsigned short*)(ws + 72 * MB);  // 16 MB
  unsigned short* wob  = (unsigned short*)(ws + 88 * MB);  // 8 MB (if room)
  unsigned short* Yb   = xb;   // x dead after QKV projection; alias.

  const int wo_in_prep = (ws_size >= 97 * MB) ? 1 : 0;

  prep<<<dim3(8192, wo_in_prep ? 5 : 4), 256, 0, stream>>>(
      x, wq, wk, wv, wo, xb, wbuf, wob);
  gemm8_qkv<<<dim3(48, 16), 512, 0, stream>>>(xb, wbuf, Qb, Kb, Vb, DIMC);
  rope_kernel<<<dim3(4096), 256, 0, stream>>>(Qb, Kb);
  fattn<<<dim3(512), 256, 0, stream>>>(Qb, Kb, Vb, Yb);
  const unsigned short* wo_b;
  if (wo_in_prep) {
    wo_b = wob;
  } else {
    dequant_auto<<<dim3(8192), 256, 0, stream>>>(wo, x, wbuf);
    wo_b = wbuf;
  }
  gemm8_bt<<<dim3(16, 16), 512, 0, stream>>>(Yb, wo_b, out, DIMC, DIMC);
}